// Round 9
// baseline (753.497 us; speedup 1.0000x reference)
//
#include <hip/hip_runtime.h>
#include <hip/hip_bf16.h>

#define NE 16
#define H  2048
#define I  768
#define TK 8
#define NT 4096

typedef unsigned short u16;
typedef unsigned int u32;
typedef __attribute__((ext_vector_type(8))) short bf16x8;
typedef __attribute__((ext_vector_type(4))) float f32x4;

__device__ __forceinline__ u16 f2bf(float f) {
    u32 u = __float_as_uint(f);
    u32 r = (u + 0x7fffu + ((u >> 16) & 1u)) >> 16;
    return (u16)r;
}

__device__ __forceinline__ void gload16(const void* g, void* l) {
    __builtin_amdgcn_global_load_lds(
        (const __attribute__((address_space(1))) unsigned int*)g,
        (__attribute__((address_space(3))) unsigned int*)l, 16, 0, 0);
}

// ---- 8-phase template plumbing ----
__device__ __forceinline__ void BAR() {
    __builtin_amdgcn_sched_barrier(0);
    __builtin_amdgcn_s_barrier();
    __builtin_amdgcn_sched_barrier(0);
}
__device__ __forceinline__ void WLDS() {
    asm volatile("s_waitcnt lgkmcnt(0)" ::: "memory");
    __builtin_amdgcn_sched_barrier(0);
}
#define VM4() asm volatile("s_waitcnt vmcnt(4)" ::: "memory")

#define MF(a, b, c) __builtin_amdgcn_mfma_f32_16x16x32_bf16(a, b, c, 0, 0, 0)

// swizzled frag read: logical k-slot q, stored slot q ^ ((row>>1)&3)
#define FRAG(REG, ROW) (*(const bf16x8*)((REG) + (ROW)*32 + ((q ^ ((((ROW) >> 1)) & 3)) * 8)))

// stage one 256x32 K-half: 2 x global_load_lds(16B) per thread, linear LDS dest
#define STG(PR0, PR1, DST, KO)                       \
    do {                                             \
        gload16((PR0) + (KO), (DST) + tid * 8);      \
        gload16((PR1) + (KO), (DST) + 4096 + tid * 8); \
    } while (0)

#define MFMA_Q(MH)                                                                     \
    do {                                                                               \
        acc[(MH)*4+0][0]=MF(af0,bf0,acc[(MH)*4+0][0]); acc[(MH)*4+0][1]=MF(af0,bf1,acc[(MH)*4+0][1]); \
        acc[(MH)*4+0][2]=MF(af0,bf2,acc[(MH)*4+0][2]); acc[(MH)*4+0][3]=MF(af0,bf3,acc[(MH)*4+0][3]); \
        acc[(MH)*4+1][0]=MF(af1,bf0,acc[(MH)*4+1][0]); acc[(MH)*4+1][1]=MF(af1,bf1,acc[(MH)*4+1][1]); \
        acc[(MH)*4+1][2]=MF(af1,bf2,acc[(MH)*4+1][2]); acc[(MH)*4+1][3]=MF(af1,bf3,acc[(MH)*4+1][3]); \
        acc[(MH)*4+2][0]=MF(af2,bf0,acc[(MH)*4+2][0]); acc[(MH)*4+2][1]=MF(af2,bf1,acc[(MH)*4+2][1]); \
        acc[(MH)*4+2][2]=MF(af2,bf2,acc[(MH)*4+2][2]); acc[(MH)*4+2][3]=MF(af2,bf3,acc[(MH)*4+2][3]); \
        acc[(MH)*4+3][0]=MF(af3,bf0,acc[(MH)*4+3][0]); acc[(MH)*4+3][1]=MF(af3,bf1,acc[(MH)*4+3][1]); \
        acc[(MH)*4+3][2]=MF(af3,bf2,acc[(MH)*4+3][2]); acc[(MH)*4+3][3]=MF(af3,bf3,acc[(MH)*4+3][3]); \
    } while (0)

// one K-tile = 4 phases. Stage schedule (dead-at-issue verified):
//  p1 -> other-buf A ks1 (tile T1), p2 -> other-buf B ks1 (T1),
//  p3 -> own-buf A ks0 (tile T2),  p4 -> own-buf B ks0 (T2) + vmcnt(4)
#define KTILE(cA0, cA1, cB0, cB1, oA1, oB1, T1, T2)                           \
    do {                                                                      \
        af0 = FRAG(cA0, wm*128 +  0 + ln); af1 = FRAG(cA0, wm*128 + 16 + ln); \
        af2 = FRAG(cA0, wm*128 + 32 + ln); af3 = FRAG(cA0, wm*128 + 48 + ln); \
        bf0 = FRAG(cB0, wn*64 +  0 + ln);  bf1 = FRAG(cB0, wn*64 + 16 + ln);  \
        bf2 = FRAG(cB0, wn*64 + 32 + ln);  bf3 = FRAG(cB0, wn*64 + 48 + ln);  \
        STG(pA0, pA1, oA1, (T1)*64 + 32);                                     \
        BAR(); WLDS();                                                        \
        __builtin_amdgcn_s_setprio(1); MFMA_Q(0); __builtin_amdgcn_s_setprio(0); \
        BAR();                                                                \
        af0 = FRAG(cA0, wm*128 + 64 + ln); af1 = FRAG(cA0, wm*128 + 80 + ln); \
        af2 = FRAG(cA0, wm*128 + 96 + ln); af3 = FRAG(cA0, wm*128 +112 + ln); \
        STG(pB0, pB1, oB1, (T1)*64 + 32);                                     \
        BAR(); WLDS();                                                        \
        __builtin_amdgcn_s_setprio(1); MFMA_Q(1); __builtin_amdgcn_s_setprio(0); \
        BAR();                                                                \
        af0 = FRAG(cA1, wm*128 +  0 + ln); af1 = FRAG(cA1, wm*128 + 16 + ln); \
        af2 = FRAG(cA1, wm*128 + 32 + ln); af3 = FRAG(cA1, wm*128 + 48 + ln); \
        bf0 = FRAG(cB1, wn*64 +  0 + ln);  bf1 = FRAG(cB1, wn*64 + 16 + ln);  \
        bf2 = FRAG(cB1, wn*64 + 32 + ln);  bf3 = FRAG(cB1, wn*64 + 48 + ln);  \
        STG(pA0, pA1, cA0, (T2)*64);                                          \
        BAR(); WLDS();                                                        \
        __builtin_amdgcn_s_setprio(1); MFMA_Q(0); __builtin_amdgcn_s_setprio(0); \
        BAR();                                                                \
        af0 = FRAG(cA1, wm*128 + 64 + ln); af1 = FRAG(cA1, wm*128 + 80 + ln); \
        af2 = FRAG(cA1, wm*128 + 96 + ln); af3 = FRAG(cA1, wm*128 +112 + ln); \
        STG(pB0, pB1, cB0, (T2)*64);                                          \
        VM4();                                                                \
        BAR(); WLDS();                                                        \
        __builtin_amdgcn_s_setprio(1); MFMA_Q(1); __builtin_amdgcn_s_setprio(0); \
        BAR();                                                                \
    } while (0)

#define GEMM_PRO_AND_DECLS()                                                  \
    u16* const sA00 = sm;         u16* const sA01 = sm + 8192;                \
    u16* const sA10 = sm + 16384; u16* const sA11 = sm + 24576;               \
    u16* const sB00 = sm + 32768; u16* const sB01 = sm + 40960;               \
    u16* const sB10 = sm + 49152; u16* const sB11 = sm + 57344;               \
    f32x4 acc[8][4];                                                          \
    _Pragma("unroll") for (int _i = 0; _i < 8; _i++)                          \
    _Pragma("unroll") for (int _j = 0; _j < 4; _j++) acc[_i][_j] = (f32x4)0.0f; \
    bf16x8 af0, af1, af2, af3, bf0, bf1, bf2, bf3;                            \
    /* prologue: halves for tile0 (all 4) + tile1 ks0 (A,B), then vmcnt(4) */ \
    STG(pA0, pA1, sA00, 0);  STG(pB0, pB1, sB00, 0);                          \
    STG(pA0, pA1, sA01, 32); STG(pB0, pB1, sB01, 32);                         \
    STG(pA0, pA1, sA10, 64); STG(pB0, pB1, sB10, 64);                         \
    VM4(); BAR();

// ---------------- fused routing: count/reserve -> prefix -> finalize ----------------
// single block; replaces route+prefix+compact+2 memsets. tslot doubles as scratch
// (packed e|mult<<4|pos<<8 in pass 1, final slot id in pass 2).
__global__ __launch_bounds__(1024) void route_fused(
    const float* __restrict__ rw, const int* __restrict__ ridx,
    int* __restrict__ cnt, int* __restrict__ base,
    int* __restrict__ tok, float* __restrict__ wt,
    int* __restrict__ tjc, int* __restrict__ tslot) {
    __shared__ int scnt[NE];
    __shared__ int sbase[NE + 1];
    int tid = threadIdx.x;
    if (tid < NE) scnt[tid] = 0;
    __syncthreads();
    for (int t = tid; t < NT; t += 1024) {
        int idx[TK];
#pragma unroll
        for (int k = 0; k < TK; k++) idx[k] = ridx[t * TK + k];
        int j = 0;
#pragma unroll
        for (int k = 0; k < TK; k++) {
            int e = idx[k];
            bool first = true;
#pragma unroll
            for (int k2 = 0; k2 < TK; k2++)
                if (k2 < k && idx[k2] == e) first = false;
            if (first) {
                int mult = 0;
#pragma unroll
                for (int k2 = 0; k2 < TK; k2++) mult += (idx[k2] == e) ? 1 : 0;
                int pos = atomicAdd(&scnt[e], 1);
                tslot[t * TK + j] = e | (mult << 4) | (pos << 8);
                j++;
            }
        }
        tjc[t] = j;
    }
    __syncthreads();
    if (tid == 0) {
        int s = 0;
        for (int e = 0; e < NE; e++) { sbase[e] = s; s += scnt[e]; }
        sbase[NE] = s;
    }
    __syncthreads();
    if (tid < NE) { cnt[tid] = scnt[tid]; base[tid] = sbase[tid]; }
    if (tid == 16) base[NE] = sbase[NE];
    for (int t = tid; t < NT; t += 1024) {
        int j = tjc[t];
        for (int k = 0; k < j; k++) {
            int pk = tslot[t * TK + k];
            int e = pk & 15, mult = (pk >> 4) & 15, pos = pk >> 8;
            int slot = sbase[e] + pos;
            tok[slot] = t;
            wt[slot] = (float)mult * rw[t * NE + e];
            tslot[t * TK + k] = slot;
        }
    }
}

// ---------------- fp32 -> bf16 convert ----------------
__global__ void cvt_hs(const float4* __restrict__ in, uint4* __restrict__ out, int n) {
    int i = blockIdx.x * 256 + threadIdx.x;
    if (i >= n) return;
    float4 a = in[i * 2], b = in[i * 2 + 1];
    uint4 o;
    o.x = (u32)f2bf(a.x) | ((u32)f2bf(a.y) << 16);
    o.y = (u32)f2bf(a.z) | ((u32)f2bf(a.w) << 16);
    o.z = (u32)f2bf(b.x) | ((u32)f2bf(b.y) << 16);
    o.w = (u32)f2bf(b.z) | ((u32)f2bf(b.w) << 16);
    out[i] = o;
}

// transpose + convert: in[e][K][N] f32 -> out[e][N][K] bf16
// float4 reads (16B/lane), uint4 packed-8 bf16 writes (16B/lane)
__global__ void transpose_cvt(const float* __restrict__ in, uint4* __restrict__ out,
                              int K, int N) {
    __shared__ float tile[64][65];
    const float* src = in + (size_t)blockIdx.z * K * N;
    uint4* dst = out + (size_t)blockIdx.z * ((size_t)K * N / 8);
    int n0 = blockIdx.x * 64, k0 = blockIdx.y * 64;
    int tid = threadIdx.x;
    int rc = (tid & 15) * 4;   // n within tile
    int rr = tid >> 4;         // k row 0..15
#pragma unroll
    for (int p = 0; p < 4; p++) {
        int r = rr + p * 16;
        float4 v = *(const float4*)&src[(size_t)(k0 + r) * N + n0 + rc];
        tile[r][rc] = v.x; tile[r][rc + 1] = v.y;
        tile[r][rc + 2] = v.z; tile[r][rc + 3] = v.w;
    }
    __syncthreads();
    int wk = (tid & 7) * 8;    // k octet
    int wn = tid >> 3;         // n 0..31
#pragma unroll
    for (int p = 0; p < 2; p++) {
        int n = wn + p * 32;
        u32 a = (u32)f2bf(tile[wk + 0][n]) | ((u32)f2bf(tile[wk + 1][n]) << 16);
        u32 b = (u32)f2bf(tile[wk + 2][n]) | ((u32)f2bf(tile[wk + 3][n]) << 16);
        u32 c = (u32)f2bf(tile[wk + 4][n]) | ((u32)f2bf(tile[wk + 5][n]) << 16);
        u32 d = (u32)f2bf(tile[wk + 6][n]) | ((u32)f2bf(tile[wk + 7][n]) << 16);
        dst[((size_t)(n0 + n) * K + k0 + wk) / 8] = make_uint4(a, b, c, d);
    }
}

// ---------------- GEMM1 (8-phase 256x256): gathered hs x W1^T, fused SwiGLU ----------------
// B-tile rows interleave gate/up at 16-col granularity: b = 32g + 16u + r
// -> global W1t row = 768u + nt*128 + g*16 + r. SwiGLU pairing lane-local.
__global__ __launch_bounds__(512, 2) void gemm1_kernel(
    const u16* __restrict__ hsb, const u16* __restrict__ w1t, u16* __restrict__ inter,
    const int* __restrict__ tok, const int* __restrict__ cnt, const int* __restrict__ base) {
    __shared__ u16 sm[65536];
    int bid = blockIdx.x;
    int lid = (bid & 7) * (1536 / 8) + (bid >> 3);
    int mt = lid & 15;
    int r2 = lid >> 4;
    int nt = r2 % 6, e = r2 / 6;
    int cn = cnt[e];
    if (mt * 256 >= cn) return;
    int b0 = base[e];

    int tid = threadIdx.x;
    int lane = tid & 63, wid = tid >> 6;
    int wm = wid >> 2, wn = wid & 3;
    int ln = lane & 15, q = lane >> 4;

    // staging constants: thread owns rows r0 (round 0) and r0+128 (round 1), k-slot sl
    int r0 = tid >> 2;
    int sl = (tid & 3) ^ ((r0 >> 1) & 3);
    int ta = b0 + min(mt * 256 + r0, cn - 1);
    int tb = b0 + min(mt * 256 + r0 + 128, cn - 1);
    const u16* pA0 = hsb + (size_t)tok[ta] * H + sl * 8;
    const u16* pA1 = hsb + (size_t)tok[tb] * H + sl * 8;
    int g0 = r0 >> 5, u0 = (r0 >> 4) & 1, rr0 = r0 & 15;
    int b1r = r0 + 128;
    int g1 = b1r >> 5, u1 = (b1r >> 4) & 1, rr1 = b1r & 15;
    const u16* pB0 = w1t + (size_t)e * 1536 * H + (size_t)(768 * u0 + nt * 128 + g0 * 16 + rr0) * H + sl * 8;
    const u16* pB1 = w1t + (size_t)e * 1536 * H + (size_t)(768 * u1 + nt * 128 + g1 * 16 + rr1) * H + sl * 8;

    GEMM_PRO_AND_DECLS();

    for (int t = 0; t < 32; t += 2) {
        int u2 = t + 2; if (u2 >= 32) u2 -= 32;
        int u3 = t + 3; if (u3 >= 32) u3 -= 32;
        KTILE(sA00, sA01, sB00, sB01, sA11, sB11, t + 1, u2);
        KTILE(sA10, sA11, sB10, sB11, sA01, sB01, u2, u3);
    }

    // epilogue: SwiGLU, write inter[slot][I]
    int jr = q * 4;
#pragma unroll
    for (int mf = 0; mf < 8; mf++) {
#pragma unroll
        for (int j = 0; j < 4; j++) {
            int rg = mt * 256 + wm * 128 + mf * 16 + jr + j;
            if (rg < cn) {
                size_t slot = (size_t)(b0 + rg);
#pragma unroll
                for (int p = 0; p < 2; p++) {
                    float gg = acc[mf][2 * p][j];
                    float uu = acc[mf][2 * p + 1][j];
                    float sv = gg / (1.0f + __expf(-gg)) * uu;
                    inter[slot * I + nt * 128 + (2 * wn + p) * 16 + ln] = f2bf(sv);
                }
            }
        }
    }
}

// ---------------- GEMM2 (8-phase 256x256): inter x W2^T -> eo[slot][H] bf16 ----------------
__global__ __launch_bounds__(512, 2) void gemm2_kernel(
    const u16* __restrict__ inter, const u16* __restrict__ w2t, u16* __restrict__ eo,
    const int* __restrict__ cnt, const int* __restrict__ base) {
    __shared__ u16 sm[65536];
    int bid = blockIdx.x;
    int lid = (bid & 7) * (2048 / 8) + (bid >> 3);
    int mt = lid & 15;
    int r2 = lid >> 4;
    int nt = r2 & 7, e = r2 >> 3;
    int cn = cnt[e];
    if (mt * 256 >= cn) return;
    int b0 = base[e];

    int tid = threadIdx.x;
    int lane = tid & 63, wid = tid >> 6;
    int wm = wid >> 2, wn = wid & 3;
    int ln = lane & 15, q = lane >> 4;

    int r0 = tid >> 2;
    int sl = (tid & 3) ^ ((r0 >> 1) & 3);
    const u16* pA0 = inter + (size_t)(b0 + mt * 256 + r0) * I + sl * 8;
    const u16* pA1 = inter + (size_t)(b0 + mt * 256 + r0 + 128) * I + sl * 8;
    const u16* pB0 = w2t + (size_t)e * H * I + (size_t)(nt * 256 + r0) * I + sl * 8;
    const u16* pB1 = w2t + (size_t)e * H * I + (size_t)(nt * 256 + r0 + 128) * I + sl * 8;

    GEMM_PRO_AND_DECLS();

    for (int t = 0; t < 12; t += 2) {
        int u2 = t + 2; if (u2 >= 12) u2 -= 12;
        int u3 = t + 3; if (u3 >= 12) u3 -= 12;
        KTILE(sA00, sA01, sB00, sB01, sA11, sB11, t + 1, u2);
        KTILE(sA10, sA11, sB10, sB11, sA01, sB01, u2, u3);
    }

    int jr = q * 4;
#pragma unroll
    for (int mf = 0; mf < 8; mf++) {
#pragma unroll
        for (int j = 0; j < 4; j++) {
            int rg = mt * 256 + wm * 128 + mf * 16 + jr + j;
            if (rg < cn) {
                u16* row = eo + (size_t)(b0 + rg) * H + nt * 256 + wn * 64;
#pragma unroll
                for (int n = 0; n < 4; n++)
                    row[n * 16 + ln] = f2bf(acc[mf][n][j]);
            }
        }
    }
}

// ---------------- combine: out[t] = sum_j wt[slot_j] * eo[slot_j] ----------------
__global__ __launch_bounds__(256) void combine_kernel(
    const u16* __restrict__ eo, const float* __restrict__ wt,
    const int* __restrict__ tjc, const int* __restrict__ tslot,
    float* __restrict__ out) {
    int t = blockIdx.x;
    int c = threadIdx.x * 8;
    float acc[8];
#pragma unroll
    for (int i = 0; i < 8; i++) acc[i] = 0.0f;
    int jc = tjc[t];
    for (int j = 0; j < jc; j++) {
        int slot = tslot[t * TK + j];
        float w = wt[slot];
        uint4 v = *(const uint4*)(eo + (size_t)slot * H + c);
        acc[0] += w * __uint_as_float(v.x << 16);
        acc[1] += w * __uint_as_float(v.x & 0xffff0000u);
        acc[2] += w * __uint_as_float(v.y << 16);
        acc[3] += w * __uint_as_float(v.y & 0xffff0000u);
        acc[4] += w * __uint_as_float(v.z << 16);
        acc[5] += w * __uint_as_float(v.z & 0xffff0000u);
        acc[6] += w * __uint_as_float(v.w << 16);
        acc[7] += w * __uint_as_float(v.w & 0xffff0000u);
    }
    float4* o = (float4*)(out + (size_t)t * H + c);
    o[0] = make_float4(acc[0], acc[1], acc[2], acc[3]);
    o[1] = make_float4(acc[4], acc[5], acc[6], acc[7]);
}

extern "C" void kernel_launch(void* const* d_in, const int* in_sizes, int n_in,
                              void* d_out, int out_size, void* d_ws, size_t ws_size,
                              hipStream_t stream) {
    const float* hs  = (const float*)d_in[0];
    const float* rw  = (const float*)d_in[1];
    const int*   ri  = (const int*)d_in[2];
    const float* w1  = (const float*)d_in[3];
    const float* w2  = (const float*)d_in[4];
    float* out = (float*)d_out;

    char* ws = (char*)d_ws;
    size_t o = 0;
    auto alloc = [&](size_t bytes) { void* p = ws + o; o += (bytes + 255) & ~(size_t)255; return p; };
    int*   tok    = (int*)alloc((size_t)NT * TK * 4);
    float* wt     = (float*)alloc((size_t)NT * TK * 4);
    int*   tjc    = (int*)alloc((size_t)NT * 4);
    int*   tslot  = (int*)alloc((size_t)NT * TK * 4);
    int*   cnt    = (int*)alloc(64);
    int*   base   = (int*)alloc(128);
    u16*   hsb    = (u16*)alloc((size_t)NT * H * 2);
    u16*   w1t    = (u16*)alloc((size_t)NE * 1536 * H * 2);
    u16*   w2t    = (u16*)alloc((size_t)NE * H * I * 2);
    u16*   inter  = (u16*)alloc((size_t)(NT * TK + 256) * I * 2);
    u16*   eo     = (u16*)alloc((size_t)(NT * TK + 256) * H * 2);
    (void)ws_size;

    route_fused<<<1, 1024, 0, stream>>>(rw, ri, cnt, base, tok, wt, tjc, tslot);
    cvt_hs<<<(NT * H / 8 + 255) / 256, 256, 0, stream>>>((const float4*)hs, (uint4*)hsb, NT * H / 8);
    {
        dim3 g(1536 / 64, H / 64, NE);
        transpose_cvt<<<g, 256, 0, stream>>>(w1, (uint4*)w1t, H, 1536);
    }
    {
        dim3 g(H / 64, I / 64, NE);
        transpose_cvt<<<g, 256, 0, stream>>>(w2, (uint4*)w2t, I, H);
    }
    gemm1_kernel<<<1536, 512, 0, stream>>>(hsb, w1t, inter, tok, cnt, base);
    gemm2_kernel<<<2048, 512, 0, stream>>>(inter, w2t, eo, cnt, base);
    combine_kernel<<<NT, 256, 0, stream>>>(eo, wt, tjc, tslot, out);
}